// Round 6
// baseline (536.823 us; speedup 1.0000x reference)
//
#include <hip/hip_runtime.h>
#include <hip/hip_cooperative_groups.h>

namespace cg = cooperative_groups;

#define D 128
#define NB 1024
#define NT 256
#define EPS 1e-5f

// One cooperative kernel, phases separated by grid.sync():
//  P0 zero wsum -> P1 scatter weights -> P2 btw partials -> P3 reduce ->
//  P4 snode = embed . btw -> P5 out = s/(s+e^-eps)
__global__ __launch_bounds__(NT, 4) void fused_kernel(
    const float* __restrict__ embed,
    const float* __restrict__ weight,
    const int*   __restrict__ eidx,
    float* __restrict__ out,
    float* __restrict__ wsum,      // [nNodes]
    float* __restrict__ btw,       // [D]
    float* __restrict__ snode,     // [nNodes]
    float* __restrict__ partialT,  // [D][NB]
    int nNodes, int nEdges)
{
    cg::grid_group grid = cg::this_grid();
    __shared__ float sbtw[D];
    __shared__ float red[NT];

    const int tid  = threadIdx.x;
    const int gtid = blockIdx.x * NT + tid;
    const int gsz  = NB * NT;

    // ---- P0: zero wsum (and LDS accumulator) ----
    for (int i = gtid; i < nNodes; i += gsz) wsum[i] = 0.f;
    for (int i = tid; i < D; i += NT) sbtw[i] = 0.f;
    grid.sync();

    // ---- P1: wsum[dst] += w ----
    for (int e = gtid; e < nEdges; e += gsz) {
        const int2 p = reinterpret_cast<const int2*>(eidx)[e];
        unsafeAtomicAdd(&wsum[p.y], weight[e]);
    }
    grid.sync();

    // ---- P2: per-block partial column sums of wsum[n]*embed[n,:] ----
    {
        const int j   = tid & 31;                       // lane -> dims 4j..4j+3
        const int hw  = blockIdx.x * (NT / 32) + (tid >> 5);
        const int nhw = NB * (NT / 32);
        float4 a0 = {0.f,0.f,0.f,0.f}, a1 = {0.f,0.f,0.f,0.f};
        int n = hw;
        for (; n + nhw < nNodes; n += 2 * nhw) {
            const float w0 = wsum[n];
            const float w1 = wsum[n + nhw];
            const float4 v0 = reinterpret_cast<const float4*>(embed + (size_t)n * D)[j];
            const float4 v1 = reinterpret_cast<const float4*>(embed + (size_t)(n + nhw) * D)[j];
            a0.x += w0*v0.x; a0.y += w0*v0.y; a0.z += w0*v0.z; a0.w += w0*v0.w;
            a1.x += w1*v1.x; a1.y += w1*v1.y; a1.z += w1*v1.z; a1.w += w1*v1.w;
        }
        if (n < nNodes) {
            const float w0 = wsum[n];
            const float4 v0 = reinterpret_cast<const float4*>(embed + (size_t)n * D)[j];
            a0.x += w0*v0.x; a0.y += w0*v0.y; a0.z += w0*v0.z; a0.w += w0*v0.w;
        }
        a0.x += a1.x; a0.y += a1.y; a0.z += a1.z; a0.w += a1.w;
        atomicAdd(&sbtw[4*j+0], a0.x);
        atomicAdd(&sbtw[4*j+1], a0.y);
        atomicAdd(&sbtw[4*j+2], a0.z);
        atomicAdd(&sbtw[4*j+3], a0.w);
        __syncthreads();
        if (tid < D) partialT[(size_t)tid * NB + blockIdx.x] = sbtw[tid];
    }
    grid.sync();

    // ---- P3: btw[d] = sum_b partialT[d][b]  (blocks 0..127) ----
    if (blockIdx.x < D) {
        const float* row = partialT + (size_t)blockIdx.x * NB;
        float s = 0.f;
        for (int k = tid; k < NB; k += NT) s += row[k];
        red[tid] = s;
        __syncthreads();
        for (int off = NT / 2; off > 0; off >>= 1) {
            if (tid < off) red[tid] += red[tid + off];
            __syncthreads();
        }
        if (tid == 0) btw[blockIdx.x] = red[0];
    }
    grid.sync();

    // ---- P4: snode[n] = dot(embed[n,:], btw) ----
    {
        const int j = tid & 31;
        const float4 bt = reinterpret_cast<const float4*>(btw)[j];
        const int hw  = blockIdx.x * (NT / 32) + (tid >> 5);
        const int nhw = NB * (NT / 32);
        int n = hw;
        for (; n + nhw < nNodes; n += 2 * nhw) {
            const float4 v0 = reinterpret_cast<const float4*>(embed + (size_t)n * D)[j];
            const float4 v1 = reinterpret_cast<const float4*>(embed + (size_t)(n + nhw) * D)[j];
            float s0 = v0.x*bt.x + v0.y*bt.y + v0.z*bt.z + v0.w*bt.w;
            float s1 = v1.x*bt.x + v1.y*bt.y + v1.z*bt.z + v1.w*bt.w;
            #pragma unroll
            for (int m = 1; m < 32; m <<= 1) {
                s0 += __shfl_xor(s0, m, 64);
                s1 += __shfl_xor(s1, m, 64);
            }
            if (j == 0) { snode[n] = s0; snode[n + nhw] = s1; }
        }
        if (n < nNodes) {
            const float4 v0 = reinterpret_cast<const float4*>(embed + (size_t)n * D)[j];
            float s0 = v0.x*bt.x + v0.y*bt.y + v0.z*bt.z + v0.w*bt.w;
            #pragma unroll
            for (int m = 1; m < 32; m <<= 1) s0 += __shfl_xor(s0, m, 64);
            if (j == 0) snode[n] = s0;
        }
    }
    grid.sync();

    // ---- P5: out[e] = sigmoid(log(s)+eps) = s/(s + e^-eps) ----
    const float c = 0.9999900000499999f;   // exp(-1e-5)
    for (int e = gtid; e < nEdges; e += gsz) {
        const int src = reinterpret_cast<const int2*>(eidx)[e].x;
        const float s = snode[src];
        out[e] = s / (s + c);
    }
}

extern "C" void kernel_launch(void* const* d_in, const int* in_sizes, int n_in,
                              void* d_out, int out_size, void* d_ws, size_t ws_size,
                              hipStream_t stream) {
    const float* embed  = (const float*)d_in[0];
    const float* weight = (const float*)d_in[1];
    const int*   eidx   = (const int*)d_in[2];
    float* out = (float*)d_out;

    int nEdges = in_sizes[1];            // weight is (E,1)
    int nNodes = in_sizes[0] / D;        // embed is (N,128)

    float* wsum     = (float*)d_ws;      // [nNodes]
    float* btw      = wsum + nNodes;     // [D]
    float* snode    = btw + D;           // [nNodes]
    float* partialT = snode + nNodes;    // [D][NB] = 512 KB

    void* args[] = {
        (void*)&embed, (void*)&weight, (void*)&eidx, (void*)&out,
        (void*)&wsum, (void*)&btw, (void*)&snode, (void*)&partialT,
        (void*)&nNodes, (void*)&nEdges
    };
    hipLaunchCooperativeKernel((const void*)fused_kernel,
                               dim3(NB), dim3(NT), args, 0, stream);
}

// Round 7
// 74.383 us; speedup vs baseline: 7.2170x; 7.2170x over previous
//
#include <hip/hip_runtime.h>

#define D 128
#define NREP 8      // wsum replicas to kill atomic line contention
#define NBLK 2048   // blocks for the two dense scans
#define EPS 1e-5f

// k0: zero wsumR[NREP][nNodes]
__global__ __launch_bounds__(256) void zero_kernel(
    float4* __restrict__ p, int n4)
{
    const int i = blockIdx.x * blockDim.x + threadIdx.x;
    const int stride = gridDim.x * blockDim.x;
    const float4 z = {0.f, 0.f, 0.f, 0.f};
    for (int k = i; k < n4; k += stride) p[k] = z;
}

// k1: wsumR[e&7][dst_e] += w_e   (2 edges per thread, vectorized reads)
__global__ __launch_bounds__(256) void wsum_kernel(
    const float* __restrict__ weight,
    const int* __restrict__ eidx,
    float* __restrict__ wsumR,    // [NREP][nNodes], pre-zeroed
    int nNodes, int nEdges)
{
    const int t = blockIdx.x * blockDim.x + threadIdx.x;
    const int e0 = 2 * t;
    if (e0 + 1 < nEdges) {
        const int4  p = reinterpret_cast<const int4*>(eidx)[t];    // e0:(x,y) e0+1:(z,w)
        const float2 w = reinterpret_cast<const float2*>(weight)[t];
        unsafeAtomicAdd(&wsumR[(size_t)( e0      & (NREP-1)) * nNodes + p.y], w.x);
        unsafeAtomicAdd(&wsumR[(size_t)((e0 + 1) & (NREP-1)) * nNodes + p.w], w.y);
    } else if (e0 < nEdges) {
        const int dst = eidx[2 * e0 + 1];
        unsafeAtomicAdd(&wsumR[(size_t)(e0 & (NREP-1)) * nNodes + dst], weight[e0]);
    }
}

// k2a: per-block partial column sums (collapses replicas inline, 4 rows in flight)
__global__ __launch_bounds__(256) void btw_partial_kernel(
    const float* __restrict__ embed,
    const float* __restrict__ wsumR,   // [NREP][nNodes]
    float* __restrict__ partialT,      // [D][NBLK]
    int nNodes)
{
    __shared__ float sbtw[D];
    const int tid = threadIdx.x;
    for (int i = tid; i < D; i += 256) sbtw[i] = 0.f;
    __syncthreads();

    const int j   = tid & 31;                       // lane -> dims 4j..4j+3
    const int hw  = blockIdx.x * 8 + (tid >> 5);
    const int nhw = NBLK * 8;

    float4 a0 = {0,0,0,0}, a1 = {0,0,0,0}, a2 = {0,0,0,0}, a3 = {0,0,0,0};
    int n = hw;
    for (; n + 3 * nhw < nNodes; n += 4 * nhw) {
        float w0 = 0.f, w1 = 0.f, w2 = 0.f, w3 = 0.f;
        #pragma unroll
        for (int r = 0; r < NREP; ++r) {
            const float* ws = wsumR + (size_t)r * nNodes;
            w0 += ws[n];
            w1 += ws[n + nhw];
            w2 += ws[n + 2 * nhw];
            w3 += ws[n + 3 * nhw];
        }
        const float4 v0 = reinterpret_cast<const float4*>(embed + (size_t)n * D)[j];
        const float4 v1 = reinterpret_cast<const float4*>(embed + (size_t)(n +     nhw) * D)[j];
        const float4 v2 = reinterpret_cast<const float4*>(embed + (size_t)(n + 2 * nhw) * D)[j];
        const float4 v3 = reinterpret_cast<const float4*>(embed + (size_t)(n + 3 * nhw) * D)[j];
        a0.x += w0*v0.x; a0.y += w0*v0.y; a0.z += w0*v0.z; a0.w += w0*v0.w;
        a1.x += w1*v1.x; a1.y += w1*v1.y; a1.z += w1*v1.z; a1.w += w1*v1.w;
        a2.x += w2*v2.x; a2.y += w2*v2.y; a2.z += w2*v2.z; a2.w += w2*v2.w;
        a3.x += w3*v3.x; a3.y += w3*v3.y; a3.z += w3*v3.z; a3.w += w3*v3.w;
    }
    for (; n < nNodes; n += nhw) {
        float w0 = 0.f;
        #pragma unroll
        for (int r = 0; r < NREP; ++r) w0 += wsumR[(size_t)r * nNodes + n];
        const float4 v0 = reinterpret_cast<const float4*>(embed + (size_t)n * D)[j];
        a0.x += w0*v0.x; a0.y += w0*v0.y; a0.z += w0*v0.z; a0.w += w0*v0.w;
    }
    a0.x += a1.x + a2.x + a3.x;
    a0.y += a1.y + a2.y + a3.y;
    a0.z += a1.z + a2.z + a3.z;
    a0.w += a1.w + a2.w + a3.w;

    atomicAdd(&sbtw[4*j+0], a0.x);
    atomicAdd(&sbtw[4*j+1], a0.y);
    atomicAdd(&sbtw[4*j+2], a0.z);
    atomicAdd(&sbtw[4*j+3], a0.w);
    __syncthreads();
    if (tid < D) partialT[(size_t)tid * NBLK + blockIdx.x] = sbtw[tid];
}

// k2b: btw[d] = sum_b partialT[d][b]
__global__ __launch_bounds__(256) void btw_reduce_kernel(
    const float* __restrict__ partialT,
    float* __restrict__ btw)
{
    __shared__ float red[256];
    const int d = blockIdx.x;
    const int tid = threadIdx.x;
    float s = 0.f;
    const float* row = partialT + (size_t)d * NBLK;
    #pragma unroll
    for (int k = tid; k < NBLK; k += 256) s += row[k];
    red[tid] = s;
    __syncthreads();
    for (int off = 128; off > 0; off >>= 1) {
        if (tid < off) red[tid] += red[tid + off];
        __syncthreads();
    }
    if (tid == 0) btw[d] = red[0];
}

// k3: snode[n] = dot(embed[n,:], btw)   (4 rows in flight)
__global__ __launch_bounds__(256) void snode_kernel(
    const float* __restrict__ embed,
    const float* __restrict__ btw,
    float* __restrict__ snode,
    int nNodes)
{
    const int tid = threadIdx.x;
    const int j = tid & 31;
    const float4 bt = reinterpret_cast<const float4*>(btw)[j];
    const int hw  = blockIdx.x * 8 + (tid >> 5);
    const int nhw = NBLK * 8;

    int n = hw;
    for (; n + 3 * nhw < nNodes; n += 4 * nhw) {
        const float4 v0 = reinterpret_cast<const float4*>(embed + (size_t)n * D)[j];
        const float4 v1 = reinterpret_cast<const float4*>(embed + (size_t)(n +     nhw) * D)[j];
        const float4 v2 = reinterpret_cast<const float4*>(embed + (size_t)(n + 2 * nhw) * D)[j];
        const float4 v3 = reinterpret_cast<const float4*>(embed + (size_t)(n + 3 * nhw) * D)[j];
        float s0 = v0.x*bt.x + v0.y*bt.y + v0.z*bt.z + v0.w*bt.w;
        float s1 = v1.x*bt.x + v1.y*bt.y + v1.z*bt.z + v1.w*bt.w;
        float s2 = v2.x*bt.x + v2.y*bt.y + v2.z*bt.z + v2.w*bt.w;
        float s3 = v3.x*bt.x + v3.y*bt.y + v3.z*bt.z + v3.w*bt.w;
        #pragma unroll
        for (int m = 1; m < 32; m <<= 1) {
            s0 += __shfl_xor(s0, m, 64);
            s1 += __shfl_xor(s1, m, 64);
            s2 += __shfl_xor(s2, m, 64);
            s3 += __shfl_xor(s3, m, 64);
        }
        if (j == 0) {
            snode[n]           = s0;
            snode[n +     nhw] = s1;
            snode[n + 2 * nhw] = s2;
            snode[n + 3 * nhw] = s3;
        }
    }
    for (; n < nNodes; n += nhw) {
        const float4 v0 = reinterpret_cast<const float4*>(embed + (size_t)n * D)[j];
        float s0 = v0.x*bt.x + v0.y*bt.y + v0.z*bt.z + v0.w*bt.w;
        #pragma unroll
        for (int m = 1; m < 32; m <<= 1) s0 += __shfl_xor(s0, m, 64);
        if (j == 0) snode[n] = s0;
    }
}

// k4: out[e] = s/(s+e^-eps), 2 edges per thread
__global__ __launch_bounds__(256) void out_kernel(
    const int* __restrict__ eidx,
    const float* __restrict__ snode,
    float* __restrict__ out,
    int nEdges)
{
    const float c = 0.9999900000499999f;   // exp(-EPS)
    const int t = blockIdx.x * blockDim.x + threadIdx.x;
    const int e0 = 2 * t;
    if (e0 + 1 < nEdges) {
        const int4 p = reinterpret_cast<const int4*>(eidx)[t];
        const float sa = snode[p.x];
        const float sb = snode[p.z];
        float2 o = { sa / (sa + c), sb / (sb + c) };
        reinterpret_cast<float2*>(out)[t] = o;
    } else if (e0 < nEdges) {
        const float s = snode[eidx[2 * e0]];
        out[e0] = s / (s + c);
    }
}

extern "C" void kernel_launch(void* const* d_in, const int* in_sizes, int n_in,
                              void* d_out, int out_size, void* d_ws, size_t ws_size,
                              hipStream_t stream) {
    const float* embed  = (const float*)d_in[0];
    const float* weight = (const float*)d_in[1];
    const int*   eidx   = (const int*)d_in[2];
    float* out = (float*)d_out;

    const int nEdges = in_sizes[1];          // weight is (E,1)
    const int nNodes = in_sizes[0] / D;      // embed is (N,128)

    float* wsumR    = (float*)d_ws;                    // [NREP][nNodes] = 3.2 MB
    float* btw      = wsumR + (size_t)NREP * nNodes;   // [128]
    float* snode    = btw + D;                         // [nNodes]
    float* partialT = snode + nNodes;                  // [D][NBLK] = 1 MB

    const int nZero4  = (NREP * nNodes + 3) / 4;
    const int pBlocks = ((nEdges + 1) / 2 + 255) / 256;

    zero_kernel       <<<512,     256, 0, stream>>>((float4*)d_ws, nZero4);
    wsum_kernel       <<<pBlocks, 256, 0, stream>>>(weight, eidx, wsumR, nNodes, nEdges);
    btw_partial_kernel<<<NBLK,    256, 0, stream>>>(embed, wsumR, partialT, nNodes);
    btw_reduce_kernel <<<D,       256, 0, stream>>>(partialT, btw);
    snode_kernel      <<<NBLK,    256, 0, stream>>>(embed, btw, snode, nNodes);
    out_kernel        <<<pBlocks, 256, 0, stream>>>(eidx, snode, out, nEdges);
}

// Round 8
// 67.537 us; speedup vs baseline: 7.9485x; 1.1014x over previous
//
#include <hip/hip_runtime.h>

#define D 128
#define EPS 1e-5f
#define SCAN_ROWS 8          // consecutive rows per half-wave (in-flight MLP)
#define HW_PER_BLK 8         // 256 threads = 8 half-waves

// k0: zero wsum[nNodes]
__global__ __launch_bounds__(256) void zero_kernel(
    float4* __restrict__ p, int n4)
{
    const int i = blockIdx.x * blockDim.x + threadIdx.x;
    if (i < n4) p[i] = {0.f, 0.f, 0.f, 0.f};
}

// k1: wsum[dst_e] += w_e   (2 edges per thread, vectorized reads)
__global__ __launch_bounds__(256) void wsum_kernel(
    const float* __restrict__ weight,
    const int* __restrict__ eidx,
    float* __restrict__ wsum,     // [nNodes], pre-zeroed
    int nEdges)
{
    const int t = blockIdx.x * blockDim.x + threadIdx.x;
    const int e0 = 2 * t;
    if (e0 + 1 < nEdges) {
        const int4   p = reinterpret_cast<const int4*>(eidx)[t];
        const float2 w = reinterpret_cast<const float2*>(weight)[t];
        unsafeAtomicAdd(&wsum[p.y], w.x);
        unsafeAtomicAdd(&wsum[p.w], w.y);
    } else if (e0 < nEdges) {
        unsafeAtomicAdd(&wsum[eidx[2 * e0 + 1]], weight[e0]);
    }
}

// k2a: per-block partial column sums, 8 consecutive rows in flight per half-wave
__global__ __launch_bounds__(256, 8) void btw_partial_kernel(
    const float* __restrict__ embed,
    const float* __restrict__ wsum,
    float* __restrict__ partialT,   // [D][nScanBlk]
    int nNodes, int nScanBlk)
{
    __shared__ float sbtw[D];
    const int tid = threadIdx.x;
    for (int i = tid; i < D; i += 256) sbtw[i] = 0.f;
    __syncthreads();

    const int j  = tid & 31;                        // lane -> dims 4j..4j+3
    const int hw = blockIdx.x * HW_PER_BLK + (tid >> 5);
    const int n0 = hw * SCAN_ROWS;

    float4 acc = {0.f, 0.f, 0.f, 0.f};
    if (n0 + SCAN_ROWS <= nNodes) {
        float4 v[SCAN_ROWS];
        float  w[SCAN_ROWS];
        #pragma unroll
        for (int r = 0; r < SCAN_ROWS; ++r)
            v[r] = reinterpret_cast<const float4*>(embed + (size_t)(n0 + r) * D)[j];
        #pragma unroll
        for (int r = 0; r < SCAN_ROWS; ++r)
            w[r] = wsum[n0 + r];
        #pragma unroll
        for (int r = 0; r < SCAN_ROWS; ++r) {
            acc.x += w[r] * v[r].x;
            acc.y += w[r] * v[r].y;
            acc.z += w[r] * v[r].z;
            acc.w += w[r] * v[r].w;
        }
    } else {
        for (int r = 0; r < SCAN_ROWS && n0 + r < nNodes; ++r) {
            const float  w = wsum[n0 + r];
            const float4 v = reinterpret_cast<const float4*>(embed + (size_t)(n0 + r) * D)[j];
            acc.x += w * v.x; acc.y += w * v.y; acc.z += w * v.z; acc.w += w * v.w;
        }
    }

    atomicAdd(&sbtw[4*j+0], acc.x);
    atomicAdd(&sbtw[4*j+1], acc.y);
    atomicAdd(&sbtw[4*j+2], acc.z);
    atomicAdd(&sbtw[4*j+3], acc.w);
    __syncthreads();
    if (tid < D) partialT[(size_t)tid * nScanBlk + blockIdx.x] = sbtw[tid];
}

// k2b: btw[d] = sum_b partialT[d][b]
__global__ __launch_bounds__(256) void btw_reduce_kernel(
    const float* __restrict__ partialT,
    float* __restrict__ btw,
    int nScanBlk)
{
    __shared__ float red[256];
    const int d = blockIdx.x;
    const int tid = threadIdx.x;
    float s = 0.f;
    const float* row = partialT + (size_t)d * nScanBlk;
    for (int k = tid; k < nScanBlk; k += 256) s += row[k];
    red[tid] = s;
    __syncthreads();
    for (int off = 128; off > 0; off >>= 1) {
        if (tid < off) red[tid] += red[tid + off];
        __syncthreads();
    }
    if (tid == 0) btw[d] = red[0];
}

// k3: snode[n] = dot(embed[n,:], btw), 8 consecutive rows in flight
__global__ __launch_bounds__(256, 8) void snode_kernel(
    const float* __restrict__ embed,
    const float* __restrict__ btw,
    float* __restrict__ snode,
    int nNodes)
{
    const int tid = threadIdx.x;
    const int j = tid & 31;
    const float4 bt = reinterpret_cast<const float4*>(btw)[j];
    const int hw = blockIdx.x * HW_PER_BLK + (tid >> 5);
    const int n0 = hw * SCAN_ROWS;

    if (n0 + SCAN_ROWS <= nNodes) {
        float4 v[SCAN_ROWS];
        #pragma unroll
        for (int r = 0; r < SCAN_ROWS; ++r)
            v[r] = reinterpret_cast<const float4*>(embed + (size_t)(n0 + r) * D)[j];
        float s[SCAN_ROWS];
        #pragma unroll
        for (int r = 0; r < SCAN_ROWS; ++r)
            s[r] = v[r].x*bt.x + v[r].y*bt.y + v[r].z*bt.z + v[r].w*bt.w;
        #pragma unroll
        for (int m = 1; m < 32; m <<= 1) {
            #pragma unroll
            for (int r = 0; r < SCAN_ROWS; ++r)
                s[r] += __shfl_xor(s[r], m, 64);
        }
        if (j == 0) {
            float4 o0 = {s[0], s[1], s[2], s[3]};
            float4 o1 = {s[4], s[5], s[6], s[7]};
            reinterpret_cast<float4*>(snode + n0)[0] = o0;
            reinterpret_cast<float4*>(snode + n0)[1] = o1;
        }
    } else if (n0 < nNodes) {
        for (int r = 0; r < SCAN_ROWS && n0 + r < nNodes; ++r) {
            const float4 v = reinterpret_cast<const float4*>(embed + (size_t)(n0 + r) * D)[j];
            float s = v.x*bt.x + v.y*bt.y + v.z*bt.z + v.w*bt.w;
            #pragma unroll
            for (int m = 1; m < 32; m <<= 1) s += __shfl_xor(s, m, 64);
            if (j == 0) snode[n0 + r] = s;
        }
    }
}

// k4: out[e] = s/(s+e^-eps), 2 edges per thread
__global__ __launch_bounds__(256) void out_kernel(
    const int* __restrict__ eidx,
    const float* __restrict__ snode,
    float* __restrict__ out,
    int nEdges)
{
    const float c = 0.9999900000499999f;   // exp(-EPS)
    const int t = blockIdx.x * blockDim.x + threadIdx.x;
    const int e0 = 2 * t;
    if (e0 + 1 < nEdges) {
        const int4 p = reinterpret_cast<const int4*>(eidx)[t];
        const float sa = snode[p.x];
        const float sb = snode[p.z];
        float2 o = { sa / (sa + c), sb / (sb + c) };
        reinterpret_cast<float2*>(out)[t] = o;
    } else if (e0 < nEdges) {
        const float s = snode[eidx[2 * e0]];
        out[e0] = s / (s + c);
    }
}

extern "C" void kernel_launch(void* const* d_in, const int* in_sizes, int n_in,
                              void* d_out, int out_size, void* d_ws, size_t ws_size,
                              hipStream_t stream) {
    const float* embed  = (const float*)d_in[0];
    const float* weight = (const float*)d_in[1];
    const int*   eidx   = (const int*)d_in[2];
    float* out = (float*)d_out;

    const int nEdges = in_sizes[1];          // weight is (E,1)
    const int nNodes = in_sizes[0] / D;      // embed is (N,128)

    float* wsum     = (float*)d_ws;          // [nNodes]
    float* btw      = wsum + nNodes;         // [128]
    float* snode    = btw + D;               // [nNodes]
    float* partialT = snode + nNodes;        // [D][nScanBlk]

    const int nZero4   = (nNodes + 3) / 4;
    const int zBlocks  = (nZero4 + 255) / 256;
    const int pBlocks  = ((nEdges + 1) / 2 + 255) / 256;
    const int nScanBlk = (nNodes + SCAN_ROWS * HW_PER_BLK - 1) / (SCAN_ROWS * HW_PER_BLK);

    zero_kernel       <<<zBlocks,  256, 0, stream>>>((float4*)d_ws, nZero4);
    wsum_kernel       <<<pBlocks,  256, 0, stream>>>(weight, eidx, wsum, nEdges);
    btw_partial_kernel<<<nScanBlk, 256, 0, stream>>>(embed, wsum, partialT, nNodes, nScanBlk);
    btw_reduce_kernel <<<D,        256, 0, stream>>>(partialT, btw, nScanBlk);
    snode_kernel      <<<nScanBlk, 256, 0, stream>>>(embed, btw, snode, nNodes);
    out_kernel        <<<pBlocks,  256, 0, stream>>>(eidx, snode, out, nEdges);
}